// Round 6
// baseline (300.572 us; speedup 1.0000x reference)
//
#include <hip/hip_runtime.h>
#include <math.h>

#define Bsz 64
#define Nn  256
#define Hh  1024
#define NK  768

typedef __bf16 bf16;
typedef bf16 bf16x4 __attribute__((ext_vector_type(4)));
typedef bf16 bf16x8 __attribute__((ext_vector_type(8)));
typedef float floatx4 __attribute__((ext_vector_type(4)));

#define KT_ROWS   1026          // kTp rows per batch: h = -1 .. 1024
#define KT_BSTRIDE (KT_ROWS * 256)   // 262656 elements per batch

__device__ __forceinline__ void gl_lds16(const bf16* g, bf16* l) {
    __builtin_amdgcn_global_load_lds(
        (__attribute__((address_space(1))) void*)(g),
        (__attribute__((address_space(3))) void*)(l), 16, 0, 0);
}

__device__ __forceinline__ bf16x8 cvt8(float4 a, float4 b) {
    bf16x8 v;
    v[0] = (bf16)a.x; v[1] = (bf16)a.y; v[2] = (bf16)a.z; v[3] = (bf16)a.w;
    v[4] = (bf16)b.x; v[5] = (bf16)b.y; v[6] = (bf16)b.z; v[7] = (bf16)b.w;
    return v;
}

// ---------------------------------------------------------------------------
// Combo kernel. Blocks 0..1023: stage-1 GEMM (fp32 inputs, inline bf16 cast).
// Blocks 1024..5119: k transpose kin[b][i][h] fp32 -> kTp[b][h+1][i] bf16.
// ---------------------------------------------------------------------------
__global__ __launch_bounds__(256) void prep_gemm_kernel(
    const float* __restrict__ A32,   // f [16384][1024] fp32
    const float* __restrict__ W32,   // W_lin [768][1024] fp32
    const float* __restrict__ bias,
    const float* __restrict__ kin,   // [64][256][1024] fp32
    bf16* __restrict__ wgt3,         // [64*3][256][256]
    bf16* __restrict__ kTp)          // [64][1026][256]
{
    __shared__ bf16 smem[14336];     // gemm: As[2][4096]|Bs[2][3072]; kT: T[64*72]
    const int tid = threadIdx.x;

    if (blockIdx.x >= 1024) {
        // ---- kT path ----
        int id = blockIdx.x - 1024;            // 0..4095
        int hb = id & 15, ib = (id >> 4) & 3, b = id >> 6;
        int i0 = ib * 64, h0 = hb * 64;
        const float* src = kin + ((size_t)b << 18);
        bf16* dstb = kTp + (size_t)b * KT_BSTRIDE;
        bf16* T = smem;                        // [64][72]

        if (hb == 0 && ib == 0) {
            dstb[tid] = (bf16)0.f;                       // h = -1 row
            dstb[(size_t)1025 * 256 + tid] = (bf16)0.f;  // h = 1024 row
        }
        #pragma unroll
        for (int j = 0; j < 4; ++j) {
            int s = tid + j * 256;
            int il = s >> 4, c4 = s & 15;
            float4 v = *(const float4*)&src[(size_t)(i0 + il) * Hh + h0 + c4 * 4];
            T[(c4 * 4 + 0) * 72 + il] = (bf16)v.x;
            T[(c4 * 4 + 1) * 72 + il] = (bf16)v.y;
            T[(c4 * 4 + 2) * 72 + il] = (bf16)v.z;
            T[(c4 * 4 + 3) * 72 + il] = (bf16)v.w;
        }
        __syncthreads();
        #pragma unroll
        for (int p = 0; p < 2; ++p) {
            int hl = (tid >> 3) + p * 32;
            int q  = tid & 7;
            bf16x8 v = *(const bf16x8*)&T[hl * 72 + q * 8];
            *(bf16x8*)&dstb[(size_t)(h0 + hl + 1) * 256 + i0 + q * 8] = v;
        }
        return;
    }

    // ---- GEMM path: 128x96 tile (96 = 3 taps x 32 i), BK=64 ----
    bf16* As = smem;                 // [2][128][32]
    bf16* Bs = smem + 8192;          // [2][96][32]
    const int wave = tid >> 6, lane = tid & 63;
    const int row0 = (blockIdx.x >> 3) * 128;
    const int col0 = (blockIdx.x & 7) * 96;

    const float* gA[4]; bf16* lA[4];
    #pragma unroll
    for (int j = 0; j < 4; ++j) {
        int s = tid + j * 256;               // 0..1023
        int reg = s >> 9, rem = s & 511, row = rem >> 2, quad = rem & 3;
        gA[j] = A32 + (size_t)(row0 + row) * Hh + reg * 32 + quad * 8;
        lA[j] = As + s * 8;
    }
    const float* gB[3]; bf16* lB[3];
    #pragma unroll
    for (int j = 0; j < 3; ++j) {
        int s = tid + j * 256;               // 0..767
        int reg = s / 384, rem = s - reg * 384, row = rem >> 2, quad = rem & 3;
        gB[j] = W32 + (size_t)(col0 + row) * Hh + reg * 32 + quad * 8;
        lB[j] = Bs + s * 8;
    }

    const int wm = wave & 1, wn = wave >> 1;
    const int fm = lane & 15, koct = (lane >> 4) * 8;

    floatx4 zero = {0.f, 0.f, 0.f, 0.f};
    floatx4 acc[4][3];
    #pragma unroll
    for (int i = 0; i < 4; ++i)
        #pragma unroll
        for (int j = 0; j < 3; ++j) acc[i][j] = zero;

    for (int k0 = 0; k0 < Hh; k0 += 64) {
        float4 av[4][2], bv[3][2];
        #pragma unroll
        for (int j = 0; j < 4; ++j) {
            av[j][0] = ((const float4*)(gA[j] + k0))[0];
            av[j][1] = ((const float4*)(gA[j] + k0))[1];
        }
        #pragma unroll
        for (int j = 0; j < 3; ++j) {
            bv[j][0] = ((const float4*)(gB[j] + k0))[0];
            bv[j][1] = ((const float4*)(gB[j] + k0))[1];
        }
        __syncthreads();
        #pragma unroll
        for (int j = 0; j < 4; ++j) *(bf16x8*)lA[j] = cvt8(av[j][0], av[j][1]);
        #pragma unroll
        for (int j = 0; j < 3; ++j) *(bf16x8*)lB[j] = cvt8(bv[j][0], bv[j][1]);
        __syncthreads();
        #pragma unroll
        for (int q = 0; q < 2; ++q) {
            bf16x8 af[4], bfr[3];
            #pragma unroll
            for (int mt = 0; mt < 4; ++mt)
                af[mt] = *(const bf16x8*)&As[q * 4096 + (wm * 64 + mt * 16 + fm) * 32 + koct];
            #pragma unroll
            for (int nt = 0; nt < 3; ++nt)
                bfr[nt] = *(const bf16x8*)&Bs[q * 3072 + (wn * 48 + nt * 16 + fm) * 32 + koct];
            #pragma unroll
            for (int mt = 0; mt < 4; ++mt)
                #pragma unroll
                for (int nt = 0; nt < 3; ++nt)
                    acc[mt][nt] = __builtin_amdgcn_mfma_f32_16x16x32_bf16(
                        af[mt], bfr[nt], acc[mt][nt], 0, 0, 0);
        }
    }
    __syncthreads();

    // Epilogue: acc -> Cs[128][96] (pitch 104), then coalesced unscramble.
    const int b  = row0 >> 8;
    const int nb = row0 & 255;
    bf16* Cs = smem;
    #pragma unroll
    for (int nt = 0; nt < 3; ++nt) {
        int c = wn * 48 + nt * 16 + fm;
        float bl = bias[col0 + c];
        #pragma unroll
        for (int mt = 0; mt < 4; ++mt) {
            int rb = wm * 64 + mt * 16 + (lane >> 4) * 4;
            #pragma unroll
            for (int r = 0; r < 4; ++r)
                Cs[(rb + r) * 104 + c] = (bf16)(acc[mt][nt][r] + bl);
        }
    }
    __syncthreads();
    const int i0 = (blockIdx.x & 7) * 32;
    #pragma unroll
    for (int j = 0; j < 6; ++j) {
        int s = tid + j * 256;               // 0..1535
        int t = s / 512, rem = s & 511, n = rem >> 2, q8 = rem & 3;
        bf16x8 v;
        #pragma unroll
        for (int u = 0; u < 8; ++u)
            v[u] = Cs[n * 104 + (q8 * 8 + u) * 3 + t];
        *(bf16x8*)&wgt3[((size_t)(b * 3 + t) << 16) + ((size_t)(nb + n) << 8) + i0 + q8 * 8] = v;
    }
}

// ---------------------------------------------------------------------------
// Stage 2: out[b][o][h] = sum_{t,i} wgt3[b][t][o][i] * kTp[b][h+t][i]
// Block = (b, 64-o, 256-h) -> grid 4096 (16 blocks/CU queued, ~3 resident).
// 8 i-chunks of 32; staging via gl_lds16 (halo rows via plain load+ds write).
// ---------------------------------------------------------------------------
__global__ __launch_bounds__(256, 3) void conv_mfma(
    const bf16* __restrict__ kTp,   // [64][1026][256]
    const bf16* __restrict__ wgt3,  // [64*3][256][256]
    float* __restrict__ out)        // [64][256][1024] fp32
{
    __shared__ bf16 As[6144];       // [t][o(64)][i(32)]  12 KB
    __shared__ bf16 Ks[8256];       // [row(258)][i(32)]  16.5 KB
    const int tid  = threadIdx.x;
    const int wave = tid >> 6, lane = tid & 63;
    const int b  = blockIdx.z;
    const int o0 = blockIdx.y * 64;
    const int h0 = blockIdx.x * 256;
    const int wm = wave & 1, wn = wave >> 1;   // wm: o 32-half, wn: h 128-half
    const int fm = lane & 15, koct = (lane >> 4) * 8;

    const bf16* gA[3]; bf16* lA[3];
    #pragma unroll
    for (int j = 0; j < 3; ++j) {
        int s = tid + j * 256;               // 0..767
        int t = s >> 8, rem = s & 255, o = rem >> 2, iq = rem & 3;
        gA[j] = wgt3 + ((size_t)(b * 3 + t) << 16) + ((size_t)(o0 + o) << 8) + iq * 8;
        lA[j] = As + s * 8;
    }
    const bf16* kb = kTp + (size_t)b * KT_BSTRIDE;
    const bf16* gK[4]; bf16* lK[4];
    #pragma unroll
    for (int j = 0; j < 4; ++j) {
        int s = tid + j * 256;               // 0..1023 -> rows 0..255
        int r = s >> 2, quad = s & 3;
        gK[j] = kb + (size_t)(h0 + r) * 256 + quad * 8;
        lK[j] = Ks + s * 8;
    }

    floatx4 zero = {0.f, 0.f, 0.f, 0.f};
    floatx4 acc[2][8];
    #pragma unroll
    for (int i = 0; i < 2; ++i)
        #pragma unroll
        for (int j = 0; j < 8; ++j) acc[i][j] = zero;

    for (int ic = 0; ic < 8; ++ic) {
        const int i0 = ic * 32;
        __syncthreads();
        #pragma unroll
        for (int j = 0; j < 3; ++j) gl_lds16(gA[j] + i0, lA[j]);
        #pragma unroll
        for (int j = 0; j < 4; ++j) gl_lds16(gK[j] + i0, lK[j]);
        if (tid < 8) {                       // halo rows 256..257
            int r = 256 + (tid >> 2), q = tid & 3;
            bf16x8 v = *(const bf16x8*)&kb[(size_t)(h0 + r) * 256 + i0 + q * 8];
            *(bf16x8*)&Ks[r * 32 + q * 8] = v;
        }
        __syncthreads();
        #pragma unroll
        for (int t = 0; t < 3; ++t) {
            bf16x8 af[2], bfr[8];
            #pragma unroll
            for (int mt = 0; mt < 2; ++mt)
                af[mt] = *(const bf16x8*)&As[t * 2048 + (wm * 32 + mt * 16 + fm) * 32 + koct];
            #pragma unroll
            for (int nt = 0; nt < 8; ++nt)
                bfr[nt] = *(const bf16x8*)&Ks[(wn * 128 + nt * 16 + fm + t) * 32 + koct];
            #pragma unroll
            for (int mt = 0; mt < 2; ++mt)
                #pragma unroll
                for (int nt = 0; nt < 8; ++nt)
                    acc[mt][nt] = __builtin_amdgcn_mfma_f32_16x16x32_bf16(
                        af[mt], bfr[nt], acc[mt][nt], 0, 0, 0);
        }
    }

    #pragma unroll
    for (int mt = 0; mt < 2; ++mt) {
        int o = o0 + wm * 32 + mt * 16 + (lane >> 4) * 4;
        #pragma unroll
        for (int nt = 0; nt < 8; ++nt) {
            int h = h0 + wn * 128 + nt * 16 + fm;
            #pragma unroll
            for (int r = 0; r < 4; ++r)
                out[((size_t)(b * 256 + o + r) << 10) + h] = acc[mt][nt][r];
        }
    }
}

// ---------------------------------------------------------------------------
// Stage 3: LayerNorm over H per (b,o) row, in place on d_out (fp32).
// ---------------------------------------------------------------------------
__global__ __launch_bounds__(256) void ln_kernel(
    float* __restrict__ io, const float* __restrict__ gamma,
    const float* __restrict__ beta)
{
    const int row = blockIdx.x;
    const int tid = threadIdx.x;
    float* p = io + ((size_t)row << 10);
    float4 v = ((const float4*)p)[tid];
    float x[4] = {v.x, v.y, v.z, v.w};
    float s1 = x[0] + x[1] + x[2] + x[3];
    float s2 = x[0]*x[0] + x[1]*x[1] + x[2]*x[2] + x[3]*x[3];
    #pragma unroll
    for (int m = 1; m < 64; m <<= 1) {
        s1 += __shfl_xor(s1, m, 64);
        s2 += __shfl_xor(s2, m, 64);
    }
    __shared__ float r1[4], r2[4];
    if ((tid & 63) == 0) { r1[tid >> 6] = s1; r2[tid >> 6] = s2; }
    __syncthreads();
    float S1 = r1[0] + r1[1] + r1[2] + r1[3];
    float S2 = r2[0] + r2[1] + r2[2] + r2[3];
    float mu   = S1 * (1.0f / 1024.0f);
    float var  = S2 * (1.0f / 1024.0f) - mu * mu;
    float rstd = rsqrtf(var + 1e-5f);
    float4 g  = ((const float4*)gamma)[tid];
    float4 be = ((const float4*)beta)[tid];
    float4 o;
    o.x = (x[0] - mu) * rstd * g.x + be.x;
    o.y = (x[1] - mu) * rstd * g.y + be.y;
    o.z = (x[2] - mu) * rstd * g.z + be.z;
    o.w = (x[3] - mu) * rstd * g.w + be.w;
    ((float4*)p)[tid] = o;
}

extern "C" void kernel_launch(void* const* d_in, const int* in_sizes, int n_in,
                              void* d_out, int out_size, void* d_ws, size_t ws_size,
                              hipStream_t stream) {
    const float* f     = (const float*)d_in[0];
    const float* kin   = (const float*)d_in[1];
    const float* W_lin = (const float*)d_in[2];
    const float* b_lin = (const float*)d_in[3];
    const float* gamma = (const float*)d_in[4];
    const float* beta  = (const float*)d_in[5];
    float* out = (float*)d_out;

    char* ws = (char*)d_ws;
    bf16* kTp  = (bf16*)(ws);                   // 33.62 MB
    bf16* wgt3 = (bf16*)(ws + 33619968);        // 25.17 MB -> total ~58.8 MB

    prep_gemm_kernel<<<5120, 256, 0, stream>>>(f, W_lin, b_lin, kin, wgt3, kTp);
    conv_mfma<<<dim3(4, 4, 64), 256, 0, stream>>>(kTp, wgt3, out);
    ln_kernel<<<16384, 256, 0, stream>>>(out, gamma, beta);
}

// Round 7
// 271.560 us; speedup vs baseline: 1.1068x; 1.1068x over previous
//
#include <hip/hip_runtime.h>
#include <math.h>

#define Bsz 64
#define Nn  256
#define Hh  1024
#define NK  768

typedef __bf16 bf16;
typedef bf16 bf16x4 __attribute__((ext_vector_type(4)));
typedef bf16 bf16x8 __attribute__((ext_vector_type(8)));
typedef float floatx4 __attribute__((ext_vector_type(4)));

#define KT_ROWS   1026          // kTp rows per batch: h = -1 .. 1024
#define KT_BSTRIDE (KT_ROWS * 256)   // 262656 elements per batch

__device__ __forceinline__ void gl_lds16(const bf16* g, bf16* l) {
    __builtin_amdgcn_global_load_lds(
        (__attribute__((address_space(1))) void*)(g),
        (__attribute__((address_space(3))) void*)(l), 16, 0, 0);
}

// ---------------------------------------------------------------------------
// Prep (memory-only): blocks 0..16383 cast f->bf16; 16384..17151 cast W_lin;
// 17152..21247 transpose kin[b][i][h] fp32 -> kTp[b][h+1][i] bf16 (+halo 0s).
// ---------------------------------------------------------------------------
__global__ __launch_bounds__(256) void prep_kernel(
    const float* __restrict__ f, const float* __restrict__ wl,
    const float* __restrict__ kin,
    bf16* __restrict__ fbf, bf16* __restrict__ wlbf, bf16* __restrict__ kTp)
{
    __shared__ bf16 T[64 * 72];
    const int tid = threadIdx.x;
    const int bid = blockIdx.x;

    if (bid < 16384) {
        int i = bid * 256 + tid;
        float4 v = ((const float4*)f)[i];
        bf16x4 o = { (bf16)v.x, (bf16)v.y, (bf16)v.z, (bf16)v.w };
        ((bf16x4*)fbf)[i] = o;
        return;
    }
    if (bid < 17152) {
        int j = (bid - 16384) * 256 + tid;
        float4 v = ((const float4*)wl)[j];
        bf16x4 o = { (bf16)v.x, (bf16)v.y, (bf16)v.z, (bf16)v.w };
        ((bf16x4*)wlbf)[j] = o;
        return;
    }
    // ---- kT path ----
    int id = bid - 17152;                  // 0..4095
    int hb = id & 15, ib = (id >> 4) & 3, b = id >> 6;
    int i0 = ib * 64, h0 = hb * 64;
    const float* src = kin + ((size_t)b << 18);
    bf16* dstb = kTp + (size_t)b * KT_BSTRIDE;

    if (hb == 0 && ib == 0) {
        dstb[tid] = (bf16)0.f;                       // h = -1 row
        dstb[(size_t)1025 * 256 + tid] = (bf16)0.f;  // h = 1024 row
    }
    #pragma unroll
    for (int j = 0; j < 4; ++j) {
        int s = tid + j * 256;
        int il = s >> 4, c4 = s & 15;
        float4 v = *(const float4*)&src[(size_t)(i0 + il) * Hh + h0 + c4 * 4];
        T[(c4 * 4 + 0) * 72 + il] = (bf16)v.x;
        T[(c4 * 4 + 1) * 72 + il] = (bf16)v.y;
        T[(c4 * 4 + 2) * 72 + il] = (bf16)v.z;
        T[(c4 * 4 + 3) * 72 + il] = (bf16)v.w;
    }
    __syncthreads();
    #pragma unroll
    for (int p = 0; p < 2; ++p) {
        int hl = (tid >> 3) + p * 32;
        int q  = tid & 7;
        bf16x8 v = *(const bf16x8*)&T[hl * 72 + q * 8];
        *(bf16x8*)&dstb[(size_t)(h0 + hl + 1) * 256 + i0 + q * 8] = v;
    }
}

// ---------------------------------------------------------------------------
// Stage 1: C[row=(b,n)][col=o'] = f_bf[row,:] . W_lin[o',:]  (K=1024)
// 128x192 tile (192 = 3 taps x 64 i), BK=64, 4 waves (2m x 2n of 64x96).
// Staging via gl_lds16. Epilogue via LDS (pitch 200): +bias, unscramble to
// wgt3[b][t][n][i], coalesced 16B stores.
// ---------------------------------------------------------------------------
__global__ __launch_bounds__(256) void gemm1_mfma(
    const bf16* __restrict__ A,    // [16384][1024]
    const bf16* __restrict__ Bw,   // [768][1024]
    const float* __restrict__ bias,
    bf16* __restrict__ wgt3)       // [64*3][256][256]
{
    __shared__ bf16 smem[25600];   // staging As[2][4096]|Bs[2][6144]; epi Cs[128][200]
    bf16* As = smem;
    bf16* Bs = smem + 8192;
    const int tid  = threadIdx.x;
    const int wave = tid >> 6, lane = tid & 63;
    const int row0 = blockIdx.y * 128;
    const int col0 = blockIdx.x * 192;

    const bf16* gA[4]; bf16* lA[4];
    #pragma unroll
    for (int j = 0; j < 4; ++j) {
        int s = tid + j * 256;               // 0..1023
        int reg = s >> 9, rem = s & 511, row = rem >> 2, quad = rem & 3;
        gA[j] = A + (size_t)(row0 + row) * Hh + reg * 32 + quad * 8;
        lA[j] = As + s * 8;
    }
    const bf16* gB[6]; bf16* lB[6];
    #pragma unroll
    for (int j = 0; j < 6; ++j) {
        int s = tid + j * 256;               // 0..1535
        int reg = s / 768, rem = s - reg * 768, row = rem >> 2, quad = rem & 3;
        gB[j] = Bw + (size_t)(col0 + row) * Hh + reg * 32 + quad * 8;
        lB[j] = Bs + s * 8;
    }

    const int wm = wave & 1, wn = wave >> 1;
    const int fm = lane & 15, koct = (lane >> 4) * 8;

    floatx4 zero = {0.f, 0.f, 0.f, 0.f};
    floatx4 acc[4][6];
    #pragma unroll
    for (int i = 0; i < 4; ++i)
        #pragma unroll
        for (int j = 0; j < 6; ++j) acc[i][j] = zero;

    for (int k0 = 0; k0 < Hh; k0 += 64) {
        #pragma unroll
        for (int j = 0; j < 4; ++j) gl_lds16(gA[j] + k0, lA[j]);
        #pragma unroll
        for (int j = 0; j < 6; ++j) gl_lds16(gB[j] + k0, lB[j]);
        __syncthreads();
        #pragma unroll
        for (int q = 0; q < 2; ++q) {
            bf16x8 af[4], bfr[6];
            #pragma unroll
            for (int mt = 0; mt < 4; ++mt)
                af[mt] = *(const bf16x8*)&As[q * 4096 + (wm * 64 + mt * 16 + fm) * 32 + koct];
            #pragma unroll
            for (int nt = 0; nt < 6; ++nt)
                bfr[nt] = *(const bf16x8*)&Bs[q * 6144 + (wn * 96 + nt * 16 + fm) * 32 + koct];
            #pragma unroll
            for (int mt = 0; mt < 4; ++mt)
                #pragma unroll
                for (int nt = 0; nt < 6; ++nt)
                    acc[mt][nt] = __builtin_amdgcn_mfma_f32_16x16x32_bf16(
                        af[mt], bfr[nt], acc[mt][nt], 0, 0, 0);
        }
        __syncthreads();
    }

    // Epilogue: acc -> Cs[128][192] (pitch 200), then coalesced unscramble.
    const int b  = row0 >> 8;
    const int nb = row0 & 255;
    bf16* Cs = smem;
    #pragma unroll
    for (int nt = 0; nt < 6; ++nt) {
        int c = wn * 96 + nt * 16 + fm;
        float bl = bias[col0 + c];
        #pragma unroll
        for (int mt = 0; mt < 4; ++mt) {
            int rb = wm * 64 + mt * 16 + (lane >> 4) * 4;
            #pragma unroll
            for (int r = 0; r < 4; ++r)
                Cs[(rb + r) * 200 + c] = (bf16)(acc[mt][nt][r] + bl);
        }
    }
    __syncthreads();
    const int i0 = blockIdx.x * 64;
    #pragma unroll
    for (int j = 0; j < 12; ++j) {
        int s = tid + j * 256;               // 0..3071
        int t = s >> 10, rem = s & 1023, n = rem >> 3, q8 = rem & 7;
        bf16x8 v;
        #pragma unroll
        for (int u = 0; u < 8; ++u)
            v[u] = Cs[n * 200 + (q8 * 8 + u) * 3 + t];
        *(bf16x8*)&wgt3[((size_t)(b * 3 + t) << 16) + ((size_t)(nb + n) << 8) + i0 + q8 * 8] = v;
    }
}

// ---------------------------------------------------------------------------
// Stage 2: cbuf[b][o][h] = sum_{t,i} wgt3[b][t][o][i] * kTp[b][h+t][i]  (bf16)
// Block = (b, 64-o, 256-h) -> grid 4096. 8 i-chunks of 32; gl_lds16 staging.
// ---------------------------------------------------------------------------
__global__ __launch_bounds__(256, 3) void conv_mfma(
    const bf16* __restrict__ kTp,   // [64][1026][256]
    const bf16* __restrict__ wgt3,  // [64*3][256][256]
    bf16* __restrict__ cbuf)        // [64][256][1024] bf16
{
    __shared__ bf16 As[6144];       // [t][o(64)][i(32)]  12 KB
    __shared__ bf16 Ks[8256];       // [row(258)][i(32)]  16.5 KB
    const int tid  = threadIdx.x;
    const int wave = tid >> 6, lane = tid & 63;
    const int b  = blockIdx.z;
    const int o0 = blockIdx.y * 64;
    const int h0 = blockIdx.x * 256;
    const int wm = wave & 1, wn = wave >> 1;
    const int fm = lane & 15, koct = (lane >> 4) * 8;

    const bf16* gA[3]; bf16* lA[3];
    #pragma unroll
    for (int j = 0; j < 3; ++j) {
        int s = tid + j * 256;               // 0..767
        int t = s >> 8, rem = s & 255, o = rem >> 2, iq = rem & 3;
        gA[j] = wgt3 + ((size_t)(b * 3 + t) << 16) + ((size_t)(o0 + o) << 8) + iq * 8;
        lA[j] = As + s * 8;
    }
    const bf16* kb = kTp + (size_t)b * KT_BSTRIDE;
    const bf16* gK[4]; bf16* lK[4];
    #pragma unroll
    for (int j = 0; j < 4; ++j) {
        int s = tid + j * 256;               // 0..1023 -> rows 0..255
        int r = s >> 2, quad = s & 3;
        gK[j] = kb + (size_t)(h0 + r) * 256 + quad * 8;
        lK[j] = Ks + s * 8;
    }

    floatx4 zero = {0.f, 0.f, 0.f, 0.f};
    floatx4 acc[2][8];
    #pragma unroll
    for (int i = 0; i < 2; ++i)
        #pragma unroll
        for (int j = 0; j < 8; ++j) acc[i][j] = zero;

    for (int ic = 0; ic < 8; ++ic) {
        const int i0 = ic * 32;
        __syncthreads();
        #pragma unroll
        for (int j = 0; j < 3; ++j) gl_lds16(gA[j] + i0, lA[j]);
        #pragma unroll
        for (int j = 0; j < 4; ++j) gl_lds16(gK[j] + i0, lK[j]);
        if (tid < 8) {                       // halo rows 256..257
            int r = 256 + (tid >> 2), q = tid & 3;
            bf16x8 v = *(const bf16x8*)&kb[(size_t)(h0 + r) * 256 + i0 + q * 8];
            *(bf16x8*)&Ks[r * 32 + q * 8] = v;
        }
        __syncthreads();
        #pragma unroll
        for (int t = 0; t < 3; ++t) {
            bf16x8 af[2], bfr[8];
            #pragma unroll
            for (int mt = 0; mt < 2; ++mt)
                af[mt] = *(const bf16x8*)&As[t * 2048 + (wm * 32 + mt * 16 + fm) * 32 + koct];
            #pragma unroll
            for (int nt = 0; nt < 8; ++nt)
                bfr[nt] = *(const bf16x8*)&Ks[(wn * 128 + nt * 16 + fm + t) * 32 + koct];
            #pragma unroll
            for (int mt = 0; mt < 2; ++mt)
                #pragma unroll
                for (int nt = 0; nt < 8; ++nt)
                    acc[mt][nt] = __builtin_amdgcn_mfma_f32_16x16x32_bf16(
                        af[mt], bfr[nt], acc[mt][nt], 0, 0, 0);
        }
    }

    #pragma unroll
    for (int mt = 0; mt < 2; ++mt) {
        int o = o0 + wm * 32 + mt * 16 + (lane >> 4) * 4;
        #pragma unroll
        for (int nt = 0; nt < 8; ++nt) {
            int h = h0 + wn * 128 + nt * 16 + fm;
            #pragma unroll
            for (int r = 0; r < 4; ++r)
                cbuf[((size_t)(b * 256 + o + r) << 10) + h] = (bf16)acc[mt][nt][r];
        }
    }
}

// ---------------------------------------------------------------------------
// Stage 3: LayerNorm over H per (b,o) row; bf16 in (cbuf), fp32 out (d_out).
// ---------------------------------------------------------------------------
__global__ __launch_bounds__(256) void ln_kernel(
    const bf16* __restrict__ cbuf, const float* __restrict__ gamma,
    const float* __restrict__ beta, float* __restrict__ out)
{
    const int row = blockIdx.x;
    const int tid = threadIdx.x;
    bf16x4 v = ((const bf16x4*)(cbuf + ((size_t)row << 10)))[tid];
    float x[4] = {(float)v[0], (float)v[1], (float)v[2], (float)v[3]};
    float s1 = x[0] + x[1] + x[2] + x[3];
    float s2 = x[0]*x[0] + x[1]*x[1] + x[2]*x[2] + x[3]*x[3];
    #pragma unroll
    for (int m = 1; m < 64; m <<= 1) {
        s1 += __shfl_xor(s1, m, 64);
        s2 += __shfl_xor(s2, m, 64);
    }
    __shared__ float r1[4], r2[4];
    if ((tid & 63) == 0) { r1[tid >> 6] = s1; r2[tid >> 6] = s2; }
    __syncthreads();
    float S1 = r1[0] + r1[1] + r1[2] + r1[3];
    float S2 = r2[0] + r2[1] + r2[2] + r2[3];
    float mu   = S1 * (1.0f / 1024.0f);
    float var  = S2 * (1.0f / 1024.0f) - mu * mu;
    float rstd = rsqrtf(var + 1e-5f);
    float4 g  = ((const float4*)gamma)[tid];
    float4 be = ((const float4*)beta)[tid];
    float4 o;
    o.x = (x[0] - mu) * rstd * g.x + be.x;
    o.y = (x[1] - mu) * rstd * g.y + be.y;
    o.z = (x[2] - mu) * rstd * g.z + be.z;
    o.w = (x[3] - mu) * rstd * g.w + be.w;
    ((float4*)(out + ((size_t)row << 10)))[tid] = o;
}

extern "C" void kernel_launch(void* const* d_in, const int* in_sizes, int n_in,
                              void* d_out, int out_size, void* d_ws, size_t ws_size,
                              hipStream_t stream) {
    const float* f     = (const float*)d_in[0];
    const float* kin   = (const float*)d_in[1];
    const float* W_lin = (const float*)d_in[2];
    const float* b_lin = (const float*)d_in[3];
    const float* gamma = (const float*)d_in[4];
    const float* beta  = (const float*)d_in[5];
    float* out = (float*)d_out;

    char* ws = (char*)d_ws;
    bf16* fbf  = (bf16*)(ws);                   // 33.55 MB (dead after gemm1)
    bf16* cbuf = (bf16*)(ws);                   // 33.55 MB, aliases fbf
    bf16* wlbf = (bf16*)(ws + 33554432);        // 1.57 MB
    bf16* kTp  = (bf16*)(ws + 35127296);        // 33.62 MB
    bf16* wgt3 = (bf16*)(ws + 68747264);        // 25.17 MB -> total ~93.9 MB

    prep_kernel<<<21248, 256, 0, stream>>>(f, W_lin, kin, fbf, wlbf, kTp);
    gemm1_mfma<<<dim3(4, 128), 256, 0, stream>>>(fbf, wlbf, b_lin, wgt3);
    conv_mfma<<<dim3(4, 4, 64), 256, 0, stream>>>(kTp, wgt3, cbuf);
    ln_kernel<<<16384, 256, 0, stream>>>(cbuf, gamma, beta, out);
}